// Round 16
// baseline (123.441 us; speedup 1.0000x reference)
//
#include <hip/hip_runtime.h>
#include <hip/hip_bf16.h>
#include <cstdint>

// LinearAttention on MI355X.
//  k_pre   : rms1 one-pass x->xn^T bf16 (512 blocks x 32 px) + qkv_w f2bf
//            + den init + ctx16 zero
//  k_gemm1 : qkv_w @ xn — r16: A-operand direct global->reg (L2-resident,
//            reused 128x); LDS = Bs dbuf only (33 KB) -> 4 blocks/CU at the
//            SAME 8-kt barrier count (r15's BK=32 doubled barriers: -7 µs).
//            bm 0-3 = q -> softmax_d -> qT; bm 4-11 = head h:
//            exp(k) @ v^T -> ctx16[bn&15][h] atomics.
//  k_fold  : ctx[h] = sum_16 reps + mem-kv; M = convw fold (256 blocks)
//  k_gemm2 : d_out = rms2( M @ q' + b ) — r11 double-buffered pipeline.

typedef unsigned short u16;
typedef unsigned int   u32;
typedef short bf16x8 __attribute__((ext_vector_type(8)));
typedef float f32x4  __attribute__((ext_vector_type(4)));

#define HW    16384
#define CDIM  512
#define SQRTD 22.627416997969522f

#define WAITV0 asm volatile("s_waitcnt vmcnt(0)" ::: "memory")
#define WAITL0 asm volatile("s_waitcnt lgkmcnt(0)" ::: "memory")
#define SCHED0 __builtin_amdgcn_sched_barrier(0)

__device__ __forceinline__ u16 f2bf(float f) {
  u32 x = __builtin_bit_cast(u32, f);
  u32 r = x + 0x7fffu + ((x >> 16) & 1u);
  return (u16)(r >> 16);
}

__device__ __forceinline__ void gload16(const void* g, void* l) {
  __builtin_amdgcn_global_load_lds(
      (const __attribute__((address_space(1))) void*)(uintptr_t)g,
      (__attribute__((address_space(3))) void*)(u32)(uintptr_t)l,
      16, 0, 0);
}

// ---------------- merged prologue (512 blocks x 32 px) ------------------
__global__ __launch_bounds__(512) void k_pre(const float* __restrict__ x, const float* __restrict__ g1,
                                             const float* __restrict__ qkvw, const float* __restrict__ memkv,
                                             u16* __restrict__ xnt, u16* __restrict__ wbf,
                                             float* __restrict__ den, float* __restrict__ ctx16) {
  __shared__ float tl[512 * 33];
  __shared__ float ssp[16][32];
  __shared__ float rs[32];
  __shared__ float gl[512];
  int t = threadIdx.x, l = t & 63, w = t >> 6;
  int b = blockIdx.x;
  int p0 = b * 32;
  #pragma unroll
  for (int i = 0; i < 8; i++) {
    int idx = i * 512 + t;
    int c = idx >> 3, p4 = (idx & 7) * 4;
    float4 v = *(const float4*)(x + (size_t)c * HW + p0 + p4);
    tl[c * 33 + p4] = v.x; tl[c * 33 + p4 + 1] = v.y;
    tl[c * 33 + p4 + 2] = v.z; tl[c * 33 + p4 + 3] = v.w;
  }
  if (t < 512) gl[t] = 1.0f + g1[t];
  *(float2*)(ctx16 + (size_t)b * 1024 + t * 2) = make_float2(0.f, 0.f);
  __syncthreads();
  {
    int px = l & 31, cg = w * 2 + (l >> 5);
    float s = 0.f;
    #pragma unroll
    for (int c = 0; c < 32; c++) {
      float v = tl[(cg * 32 + c) * 33 + px];
      s += v * v;
    }
    ssp[cg][px] = s;
  }
  __syncthreads();
  if (t < 32) {
    float s = 0.f;
    #pragma unroll
    for (int j = 0; j < 16; j++) s += ssp[j][t];
    rs[t] = SQRTD * rsqrtf(s);
  }
  __syncthreads();
  #pragma unroll
  for (int i = 0; i < 16; i++) {
    int idx = i * 512 + t;
    int px = idx >> 8, c2 = (idx & 255) * 2;
    float sp = rs[px];
    float a = tl[c2 * 33 + px] * sp * gl[c2];
    float bq = tl[(c2 + 1) * 33 + px] * sp * gl[c2 + 1];
    *(u32*)&xnt[(size_t)(p0 + px) * CDIM + c2] = (u32)f2bf(a) | ((u32)f2bf(bq) << 16);
  }
  {
    int idx = (b * 512 + t) * 4;
    if (idx < 1536 * 512) {
      float4 v = *(const float4*)(qkvw + idx);
      ushort4 o; o.x = f2bf(v.x); o.y = f2bf(v.y); o.z = f2bf(v.z); o.w = f2bf(v.w);
      *(ushort4*)(wbf + idx) = o;
    }
  }
  if (b == 0 && t < 512) {
    int h = t >> 6, d = t & 63;
    const float* mk = memkv + ((size_t)h * 64 + d) * 4;
    den[t] = __expf(mk[0]) + __expf(mk[1]) + __expf(mk[2]) + __expf(mk[3]);
  }
}

// ---------------- GEMM1: A direct-from-L2, B LDS dbuf, 4 blocks/CU ------
__global__ __launch_bounds__(256, 4) void k_gemm1(const u16* __restrict__ A, const u16* __restrict__ Bt,
                                                  u16* __restrict__ qT, float* __restrict__ den,
                                                  float* __restrict__ ctx16) {
  const int K = CDIM;
  __shared__ u16 Bs[2][128 * 64];   // 32 KiB
  __shared__ float dred[2][64];
  int t = threadIdx.x;
  int lane = t & 63, w = t >> 6;
  int lq = lane >> 4, lr = lane & 15;
  int wg = blockIdx.x;
  int gt = (wg & 7) * 192 + (wg >> 3);
  int bn = gt / 12, bm = gt % 12;
  int wm = (w >> 1) * 64, wn = (w & 1) * 64;
  int h = bm - 4;
  int rb01 = (bm < 4) ? bm * 128 : 512 + h * 64;    // global row base for local rows 0..63
  int rb23 = (bm < 4) ? bm * 128 : 960 + h * 64;    // base such that +row(64..127) is correct
  // wave's A row base: wm==0 -> rows 0..63 (rb01), wm==64 -> rows 64..127 (rb23+64)
  const u16* Awave = A + (size_t)((wm == 0) ? rb01 : (rb23 + 64)) * K;
  f32x4 acc[4][4] = {};
  const u16* Bbase = Bt + (size_t)bn * 128 * K;

  auto STAGE_B = [&](int buf, int kt) {
    #pragma unroll
    for (int i = 0; i < 4; i++) {
      int s = i * 256 + t;
      int row = s >> 3, slot = (s & 7) ^ (row & 7);
      gload16(Bbase + (size_t)row * K + kt * 64 + slot * 8, &Bs[buf][(i * 256 + (w << 6)) * 8]);
    }
  };
  auto AFRAGS = [&](int kt, bf16x8* af0, bf16x8* af1) {
    #pragma unroll
    for (int mi = 0; mi < 4; mi++) {
      const u16* p = Awave + (size_t)(mi * 16 + lr) * K + kt * 64 + lq * 8;
      af0[mi] = *(const bf16x8*)p;
      af1[mi] = *(const bf16x8*)(p + 32);
    }
  };
  auto BFRAGS = [&](int buf, int kk, bf16x8* bv) {
    #pragma unroll
    for (int nj = 0; nj < 4; nj++) {
      int row = wn + nj * 16 + lr;
      int slot = ((kk << 2) + lq) ^ (row & 7);
      bv[nj] = *(const bf16x8*)&Bs[buf][row * 64 + slot * 8];
    }
  };

  STAGE_B(0, 0);
  WAITV0;
  __builtin_amdgcn_s_barrier();
  SCHED0;
  for (int kt = 0; kt < 8; kt++) {
    int buf = kt & 1;
    bf16x8 af0[4], af1[4], bv0[4], bv1[4];
    AFRAGS(kt, af0, af1);              // global->reg, L2-hot (compiler-managed waits)
    BFRAGS(buf, 0, bv0);
    if (kt < 7) STAGE_B(buf ^ 1, kt + 1);
    WAITL0;
    SCHED0;
    __builtin_amdgcn_s_setprio(1);
    #pragma unroll
    for (int mi = 0; mi < 4; mi++)
      #pragma unroll
      for (int nj = 0; nj < 4; nj++)
        acc[mi][nj] = __builtin_amdgcn_mfma_f32_16x16x32_bf16(af0[mi], bv0[nj], acc[mi][nj], 0, 0, 0);
    __builtin_amdgcn_s_setprio(0);
    BFRAGS(buf, 1, bv1);
    WAITL0;
    SCHED0;
    __builtin_amdgcn_s_setprio(1);
    #pragma unroll
    for (int mi = 0; mi < 4; mi++)
      #pragma unroll
      for (int nj = 0; nj < 4; nj++)
        acc[mi][nj] = __builtin_amdgcn_mfma_f32_16x16x32_bf16(af1[mi], bv1[nj], acc[mi][nj], 0, 0, 0);
    __builtin_amdgcn_s_setprio(0);
    if (kt < 7) {
      WAITV0;
      __builtin_amdgcn_s_barrier();
      SCHED0;
    }
  }

  if (bm < 4) {
    // q rows: softmax over d -> direct transposed qT stores
    int cm0 = bm * 128 + wm, cn0 = bn * 128 + wn;
    #pragma unroll
    for (int nj = 0; nj < 4; nj++) {
      float e[4][4];
      float s = 0.f;
      #pragma unroll
      for (int mi = 0; mi < 4; mi++)
        #pragma unroll
        for (int r = 0; r < 4; r++) { e[mi][r] = __expf(acc[mi][nj][r]); s += e[mi][r]; }
      s += __shfl_xor(s, 16);
      s += __shfl_xor(s, 32);
      float inv = 1.0f / s;
      int col = cn0 + nj * 16 + lr;
      #pragma unroll
      for (int mi = 0; mi < 4; mi++) {
        ushort4 o;
        o.x = f2bf(e[mi][0] * inv); o.y = f2bf(e[mi][1] * inv);
        o.z = f2bf(e[mi][2] * inv); o.w = f2bf(e[mi][3] * inv);
        *(ushort4*)&qT[(size_t)col * CDIM + cm0 + mi * 16 + lq * 4] = o;
      }
    }
  } else {
    // head block: exp(k) & v -> LDS ([64][128] each, in Bs[0]/Bs[1]) -> ctx MFMA
    __syncthreads();
    u16* Ks = &Bs[0][0];   // 8192 u16 = [64][128]
    u16* Vs = &Bs[1][0];
    if (w < 2) {
      #pragma unroll
      for (int mi = 0; mi < 4; mi++)
        #pragma unroll
        for (int r = 0; r < 4; r++) {
          int d = mi * 16 + lq * 4 + r;
          float rsum = 0.f;
          #pragma unroll
          for (int nj = 0; nj < 4; nj++) {
            float e = __expf(acc[mi][nj][r]);
            rsum += e;
            int px = wn + nj * 16 + lr;
            Ks[d * 128 + (((px >> 3) ^ (d & 7)) << 3) + (px & 7)] = f2bf(e);
          }
          rsum += __shfl_xor(rsum, 1); rsum += __shfl_xor(rsum, 2);
          rsum += __shfl_xor(rsum, 4); rsum += __shfl_xor(rsum, 8);
          if (lr == 0) dred[w][d] = rsum;
        }
    } else {
      #pragma unroll
      for (int mi = 0; mi < 4; mi++)
        #pragma unroll
        for (int r = 0; r < 4; r++) {
          int e = mi * 16 + lq * 4 + r;
          #pragma unroll
          for (int nj = 0; nj < 4; nj++) {
            int px = wn + nj * 16 + lr;
            Vs[e * 128 + (((px >> 3) ^ (e & 7)) << 3) + (px & 7)] = f2bf(acc[mi][nj][r]);
          }
        }
    }
    __syncthreads();
    if (t < 64) atomicAdd(&den[h * 64 + t], dred[0][t] + dred[1][t]);
    f32x4 c2[4] = {};
    #pragma unroll
    for (int ks = 0; ks < 4; ks++) {
      int ra = w * 16 + lr;
      bf16x8 a = *(const bf16x8*)&Ks[ra * 128 + (((ks * 4 + lq) ^ (ra & 7)) << 3)];
      #pragma unroll
      for (int nj = 0; nj < 4; nj++) {
        int rb2 = nj * 16 + lr;
        bf16x8 b = *(const bf16x8*)&Vs[rb2 * 128 + (((ks * 4 + lq) ^ (rb2 & 7)) << 3)];
        c2[nj] = __builtin_amdgcn_mfma_f32_16x16x32_bf16(a, b, c2[nj], 0, 0, 0);
      }
    }
    float* cp = ctx16 + ((size_t)(bn & 15) * 8 + h) * 4096;
    #pragma unroll
    for (int nj = 0; nj < 4; nj++)
      #pragma unroll
      for (int r = 0; r < 4; r++) {
        int d = w * 16 + lq * 4 + r, e = nj * 16 + lr;
        atomicAdd(&cp[d * 64 + e], c2[nj][r]);
      }
  }
}

// ---------------- fold: reduce 16 reps + mem-kv, then conv_w fold -------
__global__ __launch_bounds__(256) void k_fold(const float* __restrict__ convw, const float* __restrict__ ctx16,
                                              const float* __restrict__ den, const float* __restrict__ memkv,
                                              u16* __restrict__ Mbf) {
  __shared__ float cn[64 * 65];
  __shared__ float dn[64];
  __shared__ float emk[256];
  __shared__ float smv[256];
  int t = threadIdx.x;
  int h = blockIdx.x & 7, oc = blockIdx.x >> 3;   // 256 blocks: oc 0..31
  if (t < 64) dn[t] = 0.125f / den[h * 64 + t];
  if (t < 256) emk[t] = __expf(memkv[(size_t)h * 256 + t]);
  if (t < 256) smv[t] = memkv[(size_t)(512 * 4) + h * 256 + t];
  __syncthreads();
  #pragma unroll
  for (int i = 0; i < 16; i++) {
    int idx = i * 256 + t;
    int d = idx >> 6, e = idx & 63;
    float s = emk[d * 4] * smv[e * 4] + emk[d * 4 + 1] * smv[e * 4 + 1]
            + emk[d * 4 + 2] * smv[e * 4 + 2] + emk[d * 4 + 3] * smv[e * 4 + 3];
    #pragma unroll
    for (int rep = 0; rep < 16; rep++) s += ctx16[((size_t)rep * 8 + h) * 4096 + idx];
    cn[d * 65 + e] = s * dn[d];
  }
  __syncthreads();
  int o = oc * 16 + (t >> 4);
  int d0 = (t & 15) * 4;
  float Wr[64];
  const float* wp = convw + (size_t)o * CDIM + h * 64;
  #pragma unroll
  for (int e4 = 0; e4 < 16; e4++) {
    float4 v = *(const float4*)(wp + e4 * 4);
    Wr[e4 * 4] = v.x; Wr[e4 * 4 + 1] = v.y; Wr[e4 * 4 + 2] = v.z; Wr[e4 * 4 + 3] = v.w;
  }
  float outv[4];
  #pragma unroll
  for (int dd = 0; dd < 4; dd++) {
    float a = 0.f;
    #pragma unroll
    for (int e = 0; e < 64; e++) a += Wr[e] * cn[(d0 + dd) * 65 + e];
    outv[dd] = a;
  }
  #pragma unroll
  for (int j = 0; j < 2; j++) {
    u32 v = (u32)f2bf(outv[j * 2]) | ((u32)f2bf(outv[j * 2 + 1]) << 16);
    *(u32*)&Mbf[(size_t)o * CDIM + h * 64 + d0 + j * 2] = v;
  }
}

// ---------------- GEMM2: d_out = rms2(M @ q' + b), dbuf pipeline (r11) --
__global__ __launch_bounds__(512) void k_gemm2(const u16* __restrict__ A, const u16* __restrict__ Bt,
                                               const float* __restrict__ bias, const float* __restrict__ g2,
                                               float* __restrict__ out) {
  __shared__ u16 As[2][512 * 64];   // 128 KiB
  __shared__ u16 Bs[2][64 * 64];    // 16 KiB
  __shared__ float css[64];
  int t = threadIdx.x; int lane = t & 63, w = t >> 6, lq = lane >> 4, lr = lane & 15;
  int bn = blockIdx.x;
  if (t < 64) css[t] = 0.f;
  const u16* Bbase = Bt + (size_t)bn * 64 * CDIM;
  f32x4 acc[4][4] = {};

  auto STAGE = [&](int buf, int kt) {
    #pragma unroll
    for (int i = 0; i < 8; i++) {
      int s = i * 512 + t;
      int row = s >> 3, slot = (s & 7) ^ (row & 7);
      gload16(A + (size_t)row * CDIM + kt * 64 + slot * 8, &As[buf][(i * 512 + (w << 6)) * 8]);
    }
    {
      int row = t >> 3, slot = (t & 7) ^ (row & 7);
      gload16(Bbase + (size_t)row * CDIM + kt * 64 + slot * 8, &Bs[buf][(w << 6) * 8]);
    }
  };
  auto FRAGS = [&](int buf, int kk, bf16x8* af, bf16x8* bv) {
    #pragma unroll
    for (int mi = 0; mi < 4; mi++) {
      int row = w * 64 + mi * 16 + lr;
      int slot = ((kk << 2) + lq) ^ (row & 7);
      af[mi] = *(const bf16x8*)&As[buf][row * 64 + slot * 8];
    }
    #pragma unroll
    for (int nj = 0; nj < 4; nj++) {
      int row = nj * 16 + lr;
      int slot = ((kk << 2) + lq) ^ (row & 7);
      bv[nj] = *(const bf16x8*)&Bs[buf][row * 64 + slot * 8];
    }
  };

  STAGE(0, 0);
  WAITV0;
  __builtin_amdgcn_s_barrier();
  SCHED0;
  for (int kt = 0; kt < 8; kt++) {
    int buf = kt & 1;
    bf16x8 af0[4], bv0[4], af1[4], bv1[4];
    FRAGS(buf, 0, af0, bv0);
    if (kt < 7) STAGE(buf ^ 1, kt + 1);
    WAITL0;
    SCHED0;
    __builtin_amdgcn_s_setprio(1);
    #pragma unroll
    for (int mi = 0; mi < 4; mi++)
      #pragma unroll
      for (int nj = 0; nj < 4; nj++)
        acc[mi][nj] = __builtin_amdgcn_mfma_f32_16x16x32_bf16(af0[mi], bv0[nj], acc[mi][nj], 0, 0, 0);
    __builtin_amdgcn_s_setprio(0);
    FRAGS(buf, 1, af1, bv1);
    WAITL0;
    SCHED0;
    __builtin_amdgcn_s_setprio(1);
    #pragma unroll
    for (int mi = 0; mi < 4; mi++)
      #pragma unroll
      for (int nj = 0; nj < 4; nj++)
        acc[mi][nj] = __builtin_amdgcn_mfma_f32_16x16x32_bf16(af1[mi], bv1[nj], acc[mi][nj], 0, 0, 0);
    __builtin_amdgcn_s_setprio(0);
    if (kt < 7) {
      WAITV0;
      __builtin_amdgcn_s_barrier();
      SCHED0;
    }
  }
  __syncthreads();
  float bb[4][4];
  float ps[4] = {0.f, 0.f, 0.f, 0.f};
  #pragma unroll
  for (int mi = 0; mi < 4; mi++)
    #pragma unroll
    for (int r = 0; r < 4; r++) {
      int rowg = w * 64 + mi * 16 + lq * 4 + r;
      bb[mi][r] = bias[rowg];
      #pragma unroll
      for (int nj = 0; nj < 4; nj++) {
        float v = acc[mi][nj][r] + bb[mi][r];
        ps[nj] += v * v;
      }
    }
  #pragma unroll
  for (int nj = 0; nj < 4; nj++) {
    ps[nj] += __shfl_xor(ps[nj], 16);
    ps[nj] += __shfl_xor(ps[nj], 32);
  }
  if (lq == 0) {
    #pragma unroll
    for (int nj = 0; nj < 4; nj++) atomicAdd(&css[nj * 16 + lr], ps[nj]);
  }
  __syncthreads();
  float sc[4];
  #pragma unroll
  for (int nj = 0; nj < 4; nj++) sc[nj] = SQRTD * rsqrtf(css[nj * 16 + lr]);
  #pragma unroll
  for (int mi = 0; mi < 4; mi++)
    #pragma unroll
    for (int r = 0; r < 4; r++) {
      int rowg = w * 64 + mi * 16 + lq * 4 + r;
      float g = 1.0f + g2[rowg];
      #pragma unroll
      for (int nj = 0; nj < 4; nj++) {
        float v = acc[mi][nj][r] + bb[mi][r];
        out[(size_t)rowg * HW + bn * 64 + nj * 16 + lr] = v * sc[nj] * g;
      }
    }
}

extern "C" void kernel_launch(void* const* d_in, const int* in_sizes, int n_in,
                              void* d_out, int out_size, void* d_ws, size_t ws_size,
                              hipStream_t stream) {
  (void)in_sizes; (void)n_in; (void)out_size; (void)ws_size;
  const float* x     = (const float*)d_in[0];
  const float* g1    = (const float*)d_in[1];
  const float* qkvw  = (const float*)d_in[2];
  const float* memkv = (const float*)d_in[3];
  const float* convw = (const float*)d_in[4];
  const float* convb = (const float*)d_in[5];
  const float* g2    = (const float*)d_in[6];
  float* out = (float*)d_out;
  char* ws = (char*)d_ws;

  float* den   = (float*)(ws);               // 2048 B
  float* ctx16 = (float*)(ws + 4096);        // 2097152 B
  u16* Mbf     = (u16*)(ws + 2101248);       // 524288 B
  u16* wbf     = (u16*)(ws + 2625536);       // 1572864 B
  u16* xnt     = (u16*)(ws + 4198400);       // 16777216 B
  u16* qT      = (u16*)(ws + 20975616);      // 16777216 B -> ~36 MB total

  k_pre<<<512, 512, 0, stream>>>(x, g1, qkvw, memkv, xnt, wbf, den, ctx16);
  k_gemm1<<<1536, 256, 0, stream>>>(wbf, xnt, qT, den, ctx16);
  k_fold<<<256, 256, 0, stream>>>(convw, ctx16, den, memkv, Mbf);
  k_gemm2<<<256, 512, 0, stream>>>(Mbf, qT, convb, g2, out);
}

// Round 17
// 84.448 us; speedup vs baseline: 1.4617x; 1.4617x over previous
//
#include <hip/hip_runtime.h>
#include <hip/hip_bf16.h>
#include <cstdint>

// LinearAttention on MI355X — r17 = exact revert to r14 (best: 84.5 µs).
//  k_pre   : rms1 one-pass x->xn^T bf16 (512 blocks x 32 px) + qkv_w f2bf
//            + den init + ctx16 zero
//  k_gemm1 : qkv_w @ xn — 4-wave interleaved dbuf pipeline (2 blocks/CU).
//            bm 0-3 = q -> softmax_d -> qT; bm 4-11 = head h:
//            exp(k) @ v^T -> ctx16[bn&15][h] atomics.
//            NOTE: r15 (BK=32), r12 (8-wave), r16 (reg-A + launch_bounds(,4)
//            -> VGPR=64 spills, 91 µs) all regressed. 43 µs is this
//            structure's plateau across 6 schedule/occupancy variants.
//  k_fold  : ctx[h] = sum_16 reps + mem-kv; M = convw fold (256 blocks)
//  k_gemm2 : d_out = rms2( M @ q' + b ) — double-buffered pipeline (1 blk/CU;
//            r13 single-buffer A/B showed −4 µs regression).

typedef unsigned short u16;
typedef unsigned int   u32;
typedef short bf16x8 __attribute__((ext_vector_type(8)));
typedef float f32x4  __attribute__((ext_vector_type(4)));

#define HW    16384
#define CDIM  512
#define SQRTD 22.627416997969522f

#define WAITV0 asm volatile("s_waitcnt vmcnt(0)" ::: "memory")
#define WAITL0 asm volatile("s_waitcnt lgkmcnt(0)" ::: "memory")
#define SCHED0 __builtin_amdgcn_sched_barrier(0)

__device__ __forceinline__ u16 f2bf(float f) {
  u32 x = __builtin_bit_cast(u32, f);
  u32 r = x + 0x7fffu + ((x >> 16) & 1u);
  return (u16)(r >> 16);
}

__device__ __forceinline__ void gload16(const void* g, void* l) {
  __builtin_amdgcn_global_load_lds(
      (const __attribute__((address_space(1))) void*)(uintptr_t)g,
      (__attribute__((address_space(3))) void*)(u32)(uintptr_t)l,
      16, 0, 0);
}

// ---------------- merged prologue (512 blocks x 32 px) ------------------
__global__ __launch_bounds__(512) void k_pre(const float* __restrict__ x, const float* __restrict__ g1,
                                             const float* __restrict__ qkvw, const float* __restrict__ memkv,
                                             u16* __restrict__ xnt, u16* __restrict__ wbf,
                                             float* __restrict__ den, float* __restrict__ ctx16) {
  __shared__ float tl[512 * 33];
  __shared__ float ssp[16][32];
  __shared__ float rs[32];
  __shared__ float gl[512];
  int t = threadIdx.x, l = t & 63, w = t >> 6;
  int b = blockIdx.x;
  int p0 = b * 32;
  #pragma unroll
  for (int i = 0; i < 8; i++) {
    int idx = i * 512 + t;
    int c = idx >> 3, p4 = (idx & 7) * 4;
    float4 v = *(const float4*)(x + (size_t)c * HW + p0 + p4);
    tl[c * 33 + p4] = v.x; tl[c * 33 + p4 + 1] = v.y;
    tl[c * 33 + p4 + 2] = v.z; tl[c * 33 + p4 + 3] = v.w;
  }
  if (t < 512) gl[t] = 1.0f + g1[t];
  *(float2*)(ctx16 + (size_t)b * 1024 + t * 2) = make_float2(0.f, 0.f);
  __syncthreads();
  {
    int px = l & 31, cg = w * 2 + (l >> 5);
    float s = 0.f;
    #pragma unroll
    for (int c = 0; c < 32; c++) {
      float v = tl[(cg * 32 + c) * 33 + px];
      s += v * v;
    }
    ssp[cg][px] = s;
  }
  __syncthreads();
  if (t < 32) {
    float s = 0.f;
    #pragma unroll
    for (int j = 0; j < 16; j++) s += ssp[j][t];
    rs[t] = SQRTD * rsqrtf(s);
  }
  __syncthreads();
  #pragma unroll
  for (int i = 0; i < 16; i++) {
    int idx = i * 512 + t;
    int px = idx >> 8, c2 = (idx & 255) * 2;
    float sp = rs[px];
    float a = tl[c2 * 33 + px] * sp * gl[c2];
    float bq = tl[(c2 + 1) * 33 + px] * sp * gl[c2 + 1];
    *(u32*)&xnt[(size_t)(p0 + px) * CDIM + c2] = (u32)f2bf(a) | ((u32)f2bf(bq) << 16);
  }
  {
    int idx = (b * 512 + t) * 4;
    if (idx < 1536 * 512) {
      float4 v = *(const float4*)(qkvw + idx);
      ushort4 o; o.x = f2bf(v.x); o.y = f2bf(v.y); o.z = f2bf(v.z); o.w = f2bf(v.w);
      *(ushort4*)(wbf + idx) = o;
    }
  }
  if (b == 0 && t < 512) {
    int h = t >> 6, d = t & 63;
    const float* mk = memkv + ((size_t)h * 64 + d) * 4;
    den[t] = __expf(mk[0]) + __expf(mk[1]) + __expf(mk[2]) + __expf(mk[3]);
  }
}

// ---------------- GEMM1: qkv + fused attention contraction --------------
__global__ __launch_bounds__(256, 2) void k_gemm1(const u16* __restrict__ A, const u16* __restrict__ Bt,
                                                  u16* __restrict__ qT, float* __restrict__ den,
                                                  float* __restrict__ ctx16) {
  const int K = CDIM;
  __shared__ u16 As[2][128 * 64], Bs[2][128 * 64];   // 64 KiB
  __shared__ float dred[2][64];
  int t = threadIdx.x;
  int lane = t & 63, w = t >> 6;
  int lq = lane >> 4, lr = lane & 15;
  int wg = blockIdx.x;
  int gt = (wg & 7) * 192 + (wg >> 3);
  int bn = gt / 12, bm = gt % 12;
  int wm = (w >> 1) * 64, wn = (w & 1) * 64;
  int h = bm - 4;
  int rb01 = (bm < 4) ? bm * 128 : 512 + h * 64;    // local rows 0..63
  int rb23 = (bm < 4) ? bm * 128 : 960 + h * 64;    // local rows 64..127
  f32x4 acc[4][4] = {};
  const u16* Bbase = Bt + (size_t)bn * 128 * K;

  auto STAGE_A = [&](int buf, int kt) {
    #pragma unroll
    for (int i = 0; i < 4; i++) {
      int s = i * 256 + t;
      int row = s >> 3, slot = (s & 7) ^ (row & 7);
      int rb = (i < 2) ? rb01 : rb23;
      gload16(A + (size_t)(rb + row) * K + kt * 64 + slot * 8, &As[buf][(i * 256 + (w << 6)) * 8]);
    }
  };
  auto STAGE_B = [&](int buf, int kt) {
    #pragma unroll
    for (int i = 0; i < 4; i++) {
      int s = i * 256 + t;
      int row = s >> 3, slot = (s & 7) ^ (row & 7);
      gload16(Bbase + (size_t)row * K + kt * 64 + slot * 8, &Bs[buf][(i * 256 + (w << 6)) * 8]);
    }
  };
  auto FRAGS = [&](int buf, int kk, bf16x8* af, bf16x8* bv) {
    #pragma unroll
    for (int mi = 0; mi < 4; mi++) {
      int row = wm + mi * 16 + lr;
      int slot = ((kk << 2) + lq) ^ (row & 7);
      af[mi] = *(const bf16x8*)&As[buf][row * 64 + slot * 8];
    }
    #pragma unroll
    for (int nj = 0; nj < 4; nj++) {
      int row = wn + nj * 16 + lr;
      int slot = ((kk << 2) + lq) ^ (row & 7);
      bv[nj] = *(const bf16x8*)&Bs[buf][row * 64 + slot * 8];
    }
  };

  STAGE_A(0, 0);
  STAGE_B(0, 0);
  WAITV0;
  __builtin_amdgcn_s_barrier();
  SCHED0;
  for (int kt = 0; kt < 8; kt++) {
    int buf = kt & 1;
    bf16x8 af0[4], bv0[4], af1[4], bv1[4];
    FRAGS(buf, 0, af0, bv0);
    if (kt < 7) STAGE_A(buf ^ 1, kt + 1);
    WAITL0;
    SCHED0;
    __builtin_amdgcn_s_setprio(1);
    #pragma unroll
    for (int mi = 0; mi < 4; mi++)
      #pragma unroll
      for (int nj = 0; nj < 4; nj++)
        acc[mi][nj] = __builtin_amdgcn_mfma_f32_16x16x32_bf16(af0[mi], bv0[nj], acc[mi][nj], 0, 0, 0);
    __builtin_amdgcn_s_setprio(0);
    FRAGS(buf, 1, af1, bv1);
    if (kt < 7) STAGE_B(buf ^ 1, kt + 1);
    WAITL0;
    SCHED0;
    __builtin_amdgcn_s_setprio(1);
    #pragma unroll
    for (int mi = 0; mi < 4; mi++)
      #pragma unroll
      for (int nj = 0; nj < 4; nj++)
        acc[mi][nj] = __builtin_amdgcn_mfma_f32_16x16x32_bf16(af1[mi], bv1[nj], acc[mi][nj], 0, 0, 0);
    __builtin_amdgcn_s_setprio(0);
    if (kt < 7) {
      WAITV0;
      __builtin_amdgcn_s_barrier();
      SCHED0;
    }
  }

  if (bm < 4) {
    int cm0 = bm * 128 + wm, cn0 = bn * 128 + wn;
    #pragma unroll
    for (int nj = 0; nj < 4; nj++) {
      float e[4][4];
      float s = 0.f;
      #pragma unroll
      for (int mi = 0; mi < 4; mi++)
        #pragma unroll
        for (int r = 0; r < 4; r++) { e[mi][r] = __expf(acc[mi][nj][r]); s += e[mi][r]; }
      s += __shfl_xor(s, 16);
      s += __shfl_xor(s, 32);
      float inv = 1.0f / s;
      int col = cn0 + nj * 16 + lr;
      #pragma unroll
      for (int mi = 0; mi < 4; mi++) {
        ushort4 o;
        o.x = f2bf(e[mi][0] * inv); o.y = f2bf(e[mi][1] * inv);
        o.z = f2bf(e[mi][2] * inv); o.w = f2bf(e[mi][3] * inv);
        *(ushort4*)&qT[(size_t)col * CDIM + cm0 + mi * 16 + lq * 4] = o;
      }
    }
  } else {
    __syncthreads();
    u16* Ks = &As[0][0];
    u16* Vs = &Bs[0][0];
    if (w < 2) {
      #pragma unroll
      for (int mi = 0; mi < 4; mi++)
        #pragma unroll
        for (int r = 0; r < 4; r++) {
          int d = mi * 16 + lq * 4 + r;
          float rsum = 0.f;
          #pragma unroll
          for (int nj = 0; nj < 4; nj++) {
            float e = __expf(acc[mi][nj][r]);
            rsum += e;
            int px = wn + nj * 16 + lr;
            Ks[d * 128 + (((px >> 3) ^ (d & 7)) << 3) + (px & 7)] = f2bf(e);
          }
          rsum += __shfl_xor(rsum, 1); rsum += __shfl_xor(rsum, 2);
          rsum += __shfl_xor(rsum, 4); rsum += __shfl_xor(rsum, 8);
          if (lr == 0) dred[w][d] = rsum;
        }
    } else {
      #pragma unroll
      for (int mi = 0; mi < 4; mi++)
        #pragma unroll
        for (int r = 0; r < 4; r++) {
          int e = mi * 16 + lq * 4 + r;
          #pragma unroll
          for (int nj = 0; nj < 4; nj++) {
            int px = wn + nj * 16 + lr;
            Vs[e * 128 + (((px >> 3) ^ (e & 7)) << 3) + (px & 7)] = f2bf(acc[mi][nj][r]);
          }
        }
    }
    __syncthreads();
    if (t < 64) atomicAdd(&den[h * 64 + t], dred[0][t] + dred[1][t]);
    f32x4 c2[4] = {};
    #pragma unroll
    for (int ks = 0; ks < 4; ks++) {
      int ra = w * 16 + lr;
      bf16x8 a = *(const bf16x8*)&Ks[ra * 128 + (((ks * 4 + lq) ^ (ra & 7)) << 3)];
      #pragma unroll
      for (int nj = 0; nj < 4; nj++) {
        int rb2 = nj * 16 + lr;
        bf16x8 b = *(const bf16x8*)&Vs[rb2 * 128 + (((ks * 4 + lq) ^ (rb2 & 7)) << 3)];
        c2[nj] = __builtin_amdgcn_mfma_f32_16x16x32_bf16(a, b, c2[nj], 0, 0, 0);
      }
    }
    float* cp = ctx16 + ((size_t)(bn & 15) * 8 + h) * 4096;
    #pragma unroll
    for (int nj = 0; nj < 4; nj++)
      #pragma unroll
      for (int r = 0; r < 4; r++) {
        int d = w * 16 + lq * 4 + r, e = nj * 16 + lr;
        atomicAdd(&cp[d * 64 + e], c2[nj][r]);
      }
  }
}

// ---------------- fold: reduce 16 reps + mem-kv, then conv_w fold -------
__global__ __launch_bounds__(256) void k_fold(const float* __restrict__ convw, const float* __restrict__ ctx16,
                                              const float* __restrict__ den, const float* __restrict__ memkv,
                                              u16* __restrict__ Mbf) {
  __shared__ float cn[64 * 65];
  __shared__ float dn[64];
  __shared__ float emk[256];
  __shared__ float smv[256];
  int t = threadIdx.x;
  int h = blockIdx.x & 7, oc = blockIdx.x >> 3;   // 256 blocks: oc 0..31
  if (t < 64) dn[t] = 0.125f / den[h * 64 + t];
  if (t < 256) emk[t] = __expf(memkv[(size_t)h * 256 + t]);
  if (t < 256) smv[t] = memkv[(size_t)(512 * 4) + h * 256 + t];
  __syncthreads();
  #pragma unroll
  for (int i = 0; i < 16; i++) {
    int idx = i * 256 + t;
    int d = idx >> 6, e = idx & 63;
    float s = emk[d * 4] * smv[e * 4] + emk[d * 4 + 1] * smv[e * 4 + 1]
            + emk[d * 4 + 2] * smv[e * 4 + 2] + emk[d * 4 + 3] * smv[e * 4 + 3];
    #pragma unroll
    for (int rep = 0; rep < 16; rep++) s += ctx16[((size_t)rep * 8 + h) * 4096 + idx];
    cn[d * 65 + e] = s * dn[d];
  }
  __syncthreads();
  int o = oc * 16 + (t >> 4);
  int d0 = (t & 15) * 4;
  float Wr[64];
  const float* wp = convw + (size_t)o * CDIM + h * 64;
  #pragma unroll
  for (int e4 = 0; e4 < 16; e4++) {
    float4 v = *(const float4*)(wp + e4 * 4);
    Wr[e4 * 4] = v.x; Wr[e4 * 4 + 1] = v.y; Wr[e4 * 4 + 2] = v.z; Wr[e4 * 4 + 3] = v.w;
  }
  float outv[4];
  #pragma unroll
  for (int dd = 0; dd < 4; dd++) {
    float a = 0.f;
    #pragma unroll
    for (int e = 0; e < 64; e++) a += Wr[e] * cn[(d0 + dd) * 65 + e];
    outv[dd] = a;
  }
  #pragma unroll
  for (int j = 0; j < 2; j++) {
    u32 v = (u32)f2bf(outv[j * 2]) | ((u32)f2bf(outv[j * 2 + 1]) << 16);
    *(u32*)&Mbf[(size_t)o * CDIM + h * 64 + d0 + j * 2] = v;
  }
}

// ---------------- GEMM2: d_out = rms2(M @ q' + b), dbuf pipeline --------
__global__ __launch_bounds__(512) void k_gemm2(const u16* __restrict__ A, const u16* __restrict__ Bt,
                                               const float* __restrict__ bias, const float* __restrict__ g2,
                                               float* __restrict__ out) {
  __shared__ u16 As[2][512 * 64];   // 128 KiB
  __shared__ u16 Bs[2][64 * 64];    // 16 KiB
  __shared__ float css[64];
  int t = threadIdx.x; int lane = t & 63, w = t >> 6, lq = lane >> 4, lr = lane & 15;
  int bn = blockIdx.x;
  if (t < 64) css[t] = 0.f;
  const u16* Bbase = Bt + (size_t)bn * 64 * CDIM;
  f32x4 acc[4][4] = {};

  auto STAGE = [&](int buf, int kt) {
    #pragma unroll
    for (int i = 0; i < 8; i++) {
      int s = i * 512 + t;
      int row = s >> 3, slot = (s & 7) ^ (row & 7);
      gload16(A + (size_t)row * CDIM + kt * 64 + slot * 8, &As[buf][(i * 512 + (w << 6)) * 8]);
    }
    {
      int row = t >> 3, slot = (t & 7) ^ (row & 7);
      gload16(Bbase + (size_t)row * CDIM + kt * 64 + slot * 8, &Bs[buf][(w << 6) * 8]);
    }
  };
  auto FRAGS = [&](int buf, int kk, bf16x8* af, bf16x8* bv) {
    #pragma unroll
    for (int mi = 0; mi < 4; mi++) {
      int row = w * 64 + mi * 16 + lr;
      int slot = ((kk << 2) + lq) ^ (row & 7);
      af[mi] = *(const bf16x8*)&As[buf][row * 64 + slot * 8];
    }
    #pragma unroll
    for (int nj = 0; nj < 4; nj++) {
      int row = nj * 16 + lr;
      int slot = ((kk << 2) + lq) ^ (row & 7);
      bv[nj] = *(const bf16x8*)&Bs[buf][row * 64 + slot * 8];
    }
  };

  STAGE(0, 0);
  WAITV0;
  __builtin_amdgcn_s_barrier();
  SCHED0;
  for (int kt = 0; kt < 8; kt++) {
    int buf = kt & 1;
    bf16x8 af0[4], bv0[4], af1[4], bv1[4];
    FRAGS(buf, 0, af0, bv0);
    if (kt < 7) STAGE(buf ^ 1, kt + 1);
    WAITL0;
    SCHED0;
    __builtin_amdgcn_s_setprio(1);
    #pragma unroll
    for (int mi = 0; mi < 4; mi++)
      #pragma unroll
      for (int nj = 0; nj < 4; nj++)
        acc[mi][nj] = __builtin_amdgcn_mfma_f32_16x16x32_bf16(af0[mi], bv0[nj], acc[mi][nj], 0, 0, 0);
    __builtin_amdgcn_s_setprio(0);
    FRAGS(buf, 1, af1, bv1);
    WAITL0;
    SCHED0;
    __builtin_amdgcn_s_setprio(1);
    #pragma unroll
    for (int mi = 0; mi < 4; mi++)
      #pragma unroll
      for (int nj = 0; nj < 4; nj++)
        acc[mi][nj] = __builtin_amdgcn_mfma_f32_16x16x32_bf16(af1[mi], bv1[nj], acc[mi][nj], 0, 0, 0);
    __builtin_amdgcn_s_setprio(0);
    if (kt < 7) {
      WAITV0;
      __builtin_amdgcn_s_barrier();
      SCHED0;
    }
  }
  __syncthreads();
  float bb[4][4];
  float ps[4] = {0.f, 0.f, 0.f, 0.f};
  #pragma unroll
  for (int mi = 0; mi < 4; mi++)
    #pragma unroll
    for (int r = 0; r < 4; r++) {
      int rowg = w * 64 + mi * 16 + lq * 4 + r;
      bb[mi][r] = bias[rowg];
      #pragma unroll
      for (int nj = 0; nj < 4; nj++) {
        float v = acc[mi][nj][r] + bb[mi][r];
        ps[nj] += v * v;
      }
    }
  #pragma unroll
  for (int nj = 0; nj < 4; nj++) {
    ps[nj] += __shfl_xor(ps[nj], 16);
    ps[nj] += __shfl_xor(ps[nj], 32);
  }
  if (lq == 0) {
    #pragma unroll
    for (int nj = 0; nj < 4; nj++) atomicAdd(&css[nj * 16 + lr], ps[nj]);
  }
  __syncthreads();
  float sc[4];
  #pragma unroll
  for (int nj = 0; nj < 4; nj++) sc[nj] = SQRTD * rsqrtf(css[nj * 16 + lr]);
  #pragma unroll
  for (int mi = 0; mi < 4; mi++)
    #pragma unroll
    for (int r = 0; r < 4; r++) {
      int rowg = w * 64 + mi * 16 + lq * 4 + r;
      float g = 1.0f + g2[rowg];
      #pragma unroll
      for (int nj = 0; nj < 4; nj++) {
        float v = acc[mi][nj][r] + bb[mi][r];
        out[(size_t)rowg * HW + bn * 64 + nj * 16 + lr] = v * sc[nj] * g;
      }
    }
}

extern "C" void kernel_launch(void* const* d_in, const int* in_sizes, int n_in,
                              void* d_out, int out_size, void* d_ws, size_t ws_size,
                              hipStream_t stream) {
  (void)in_sizes; (void)n_in; (void)out_size; (void)ws_size;
  const float* x     = (const float*)d_in[0];
  const float* g1    = (const float*)d_in[1];
  const float* qkvw  = (const float*)d_in[2];
  const float* memkv = (const float*)d_in[3];
  const float* convw = (const float*)d_in[4];
  const float* convb = (const float*)d_in[5];
  const float* g2    = (const float*)d_in[6];
  float* out = (float*)d_out;
  char* ws = (char*)d_ws;

  float* den   = (float*)(ws);               // 2048 B
  float* ctx16 = (float*)(ws + 4096);        // 2097152 B
  u16* Mbf     = (u16*)(ws + 2101248);       // 524288 B
  u16* wbf     = (u16*)(ws + 2625536);       // 1572864 B
  u16* xnt     = (u16*)(ws + 4198400);       // 16777216 B
  u16* qT      = (u16*)(ws + 20975616);      // 16777216 B -> ~36 MB total

  k_pre<<<512, 512, 0, stream>>>(x, g1, qkvw, memkv, xnt, wbf, den, ctx16);
  k_gemm1<<<1536, 256, 0, stream>>>(wbf, xnt, qT, den, ctx16);
  k_fold<<<256, 256, 0, stream>>>(convw, ctx16, den, memkv, Mbf);
  k_gemm2<<<256, 512, 0, stream>>>(Mbf, qT, convb, g2, out);
}